// Round 1
// baseline (2148.458 us; speedup 1.0000x reference)
//
#include <hip/hip_runtime.h>
#include <hip/hip_bf16.h>
#include <math.h>

typedef __bf16 bf16;
typedef __attribute__((ext_vector_type(8))) __bf16 bf16x8;
typedef __attribute__((ext_vector_type(4))) float floatx4;

static_assert(sizeof(bf16x8) == 16, "bf16x8 must be 16B");

// ---------------------------------------------------------------------------
// Row-normalize stru_feats (8192x512 fp32) -> bf16 unit rows
// ---------------------------------------------------------------------------
__global__ void row_normalize_kernel(const float* __restrict__ x, bf16* __restrict__ out) {
  __shared__ float red[256];
  int row = blockIdx.x;
  int t = threadIdx.x;
  float v0 = x[(size_t)row * 512 + t];
  float v1 = x[(size_t)row * 512 + t + 256];
  red[t] = v0 * v0 + v1 * v1;
  __syncthreads();
  for (int d = 128; d > 0; d >>= 1) {
    if (t < d) red[t] += red[t + d];
    __syncthreads();
  }
  float scale = 1.0f / (sqrtf(red[0]) + 1e-12f);
  out[(size_t)row * 512 + t] = (bf16)(v0 * scale);
  out[(size_t)row * 512 + t + 256] = (bf16)(v1 * scale);
}

// ---------------------------------------------------------------------------
// W [K][512] fp32 -> Wt [512][K] bf16  (coalesced writes)
// ---------------------------------------------------------------------------
__global__ void transpose_cast_kernel(const float* __restrict__ W, bf16* __restrict__ Wt, int K) {
  int k0 = blockIdx.x * 64;
  int n0 = blockIdx.y * 64;
  for (int i = threadIdx.x; i < 64 * 64; i += 256) {
    int kk = i & 63, nn = i >> 6;
    Wt[(size_t)(n0 + nn) * K + (k0 + kk)] = (bf16)W[(size_t)(k0 + kk) * 512 + (n0 + nn)];
  }
}

// ---------------------------------------------------------------------------
// BN column stats over 8192 rows of H2 [8192][512]
// ---------------------------------------------------------------------------
__global__ void bn_stats_kernel(const float* __restrict__ h, float* __restrict__ colsum,
                                float* __restrict__ colsumsq) {
  int col = threadIdx.x;  // 512 threads
  int r0 = blockIdx.x * 32;
  float s = 0.f, s2 = 0.f;
  for (int r = r0; r < r0 + 32; ++r) {
    float v = h[(size_t)r * 512 + col];
    s += v;
    s2 += v * v;
  }
  atomicAdd(&colsum[col], s);
  atomicAdd(&colsumsq[col], s2);
}

// ---------------------------------------------------------------------------
// BN apply + write mm (fp32, to d_out) + row-normalized bf16 copy mmn
// ---------------------------------------------------------------------------
__global__ void bn_apply_kernel(const float* __restrict__ h, const float* __restrict__ colsum,
                                const float* __restrict__ colsumsq, const float* __restrict__ gamma,
                                const float* __restrict__ beta, float* __restrict__ mm_out,
                                bf16* __restrict__ mmn) {
  __shared__ float red[512];
  int row = blockIdx.x, col = threadIdx.x;  // 512 threads
  float mean = colsum[col] * (1.0f / 8192.0f);
  float var = colsumsq[col] * (1.0f / 8192.0f) - mean * mean;
  float inv = rsqrtf(var + 1e-5f);
  float y = (h[(size_t)row * 512 + col] - mean) * inv * gamma[col] + beta[col];
  mm_out[(size_t)row * 512 + col] = y;
  red[col] = y * y;
  __syncthreads();
  for (int d = 256; d > 0; d >>= 1) {
    if (col < d) red[col] += red[col + d];
    __syncthreads();
  }
  float scale = 1.0f / (sqrtf(red[0]) + 1e-12f);
  mmn[(size_t)row * 512 + col] = (bf16)(y * scale);
}

// ---------------------------------------------------------------------------
// Generic GEMM-NT: C[64 rows][64 cols per tile] = A[M][K] * B[N][K]^T, bf16 MFMA.
// MODE 0: +bias, leaky-relu, store bf16      (MLP layer 1)
// MODE 1: +bias, store fp32                  (MLP layer 2)
// MODE 2: per-row top-6 (partial lists)      (mmd neighbor table)
// MODE 3: rowsum(exp(2c)) + top-6 partials   (sm pass)
// ---------------------------------------------------------------------------
template <int MODE, bool AF32>
__launch_bounds__(256, 2) __global__
void gemm_nt_kernel(const void* __restrict__ Av, const bf16* __restrict__ B,
                    const float* __restrict__ bias, bf16* __restrict__ out_bf,
                    float* __restrict__ out_f, float* __restrict__ part_vals,
                    int* __restrict__ part_idx, float* __restrict__ rowsum_part, int K,
                    int ct_count, int nparts) {
  __shared__ __align__(16) bf16 As[64][72];
  __shared__ __align__(16) bf16 Bs[64][72];
  __shared__ float topv[64][6];
  __shared__ int topi[64][6];
  __shared__ float rsum[64];

  const int tid = threadIdx.x;
  const int lane = tid & 63;
  const int wave = tid >> 6;
  const int q = lane >> 4;
  const int ml = lane & 15;
  const int row0 = blockIdx.x * 64;

  if constexpr (MODE >= 2) {
    for (int i = tid; i < 64 * 6; i += 256) {
      topv[i / 6][i % 6] = -3e38f;
      topi[i / 6][i % 6] = 0;
    }
    if (tid < 64) rsum[tid] = 0.f;
    __syncthreads();
  }

  const float* Af = (const float*)Av;
  const bf16* Ab = (const bf16*)Av;

  for (int ct = 0; ct < ct_count; ++ct) {
    const int col0 = (blockIdx.y * ct_count + ct) * 64;
    floatx4 acc[4];
#pragma unroll
    for (int f = 0; f < 4; ++f) acc[f] = (floatx4)0.0f;

    for (int kt = 0; kt < K; kt += 64) {
      __syncthreads();
      for (int i = tid; i < 512; i += 256) {
        int r = i >> 3, c = (i & 7) << 3;
        if constexpr (AF32) {
          const float* p = Af + (size_t)(row0 + r) * K + kt + c;
          bf16x8 v;
#pragma unroll
          for (int e = 0; e < 8; ++e) v[e] = (bf16)p[e];
          *(bf16x8*)&As[r][c] = v;
        } else {
          *(bf16x8*)&As[r][c] = *(const bf16x8*)(Ab + (size_t)(row0 + r) * K + kt + c);
        }
        *(bf16x8*)&Bs[r][c] = *(const bf16x8*)(B + (size_t)(col0 + r) * K + kt + c);
      }
      __syncthreads();
#pragma unroll
      for (int kk = 0; kk < 64; kk += 32) {
        bf16x8 a = *(const bf16x8*)&As[wave * 16 + ml][kk + q * 8];
#pragma unroll
        for (int f = 0; f < 4; ++f) {
          bf16x8 b = *(const bf16x8*)&Bs[f * 16 + ml][kk + q * 8];
          acc[f] = __builtin_amdgcn_mfma_f32_16x16x32_bf16(a, b, acc[f], 0, 0, 0);
        }
      }
    }

    if constexpr (MODE <= 1) {
#pragma unroll
      for (int f = 0; f < 4; ++f) {
        int colg = col0 + f * 16 + ml;
        float bv = bias[colg];
#pragma unroll
        for (int i = 0; i < 4; ++i) {
          int rowg = row0 + wave * 16 + q * 4 + i;
          float v = acc[f][i] + bv;
          if constexpr (MODE == 0) {
            v = v >= 0.f ? v : 0.01f * v;
            out_bf[(size_t)rowg * 512 + colg] = (bf16)v;
          } else {
            out_f[(size_t)rowg * 512 + colg] = v;
          }
        }
      }
    } else {
      if constexpr (MODE == 3) {
#pragma unroll
        for (int i = 0; i < 4; ++i) {
          float s = 0.f;
#pragma unroll
          for (int f = 0; f < 4; ++f) s += __expf(2.0f * acc[f][i]);
          s += __shfl_xor(s, 1);
          s += __shfl_xor(s, 2);
          s += __shfl_xor(s, 4);
          s += __shfl_xor(s, 8);
          if (ml == 0) rsum[wave * 16 + q * 4 + i] += s;
        }
      }
      // top-6 maintenance, per row (owned by one 16-lane group; no atomics)
#pragma unroll
      for (int i = 0; i < 4; ++i) {
        int lrow = wave * 16 + q * 4 + i;
        float bv = acc[0][i];
        int bc = 0;
#pragma unroll
        for (int f = 1; f < 4; ++f)
          if (acc[f][i] > bv) { bv = acc[f][i]; bc = f; }
        int bcol = col0 + bc * 16 + ml;
        float thr = topv[lrow][5];
        while (true) {
          float mv = bv;
          int mc = bcol;
#pragma unroll
          for (int d = 1; d < 16; d <<= 1) {
            float ov = __shfl_xor(mv, d);
            int oc = __shfl_xor(mc, d);
            if (ov > mv || (ov == mv && oc < mc)) { mv = ov; mc = oc; }
          }
          if (!(mv > thr)) break;
          if (ml == 0) {
            int p = 6;
#pragma unroll
            for (int j = 0; j < 6; ++j)
              if (p == 6 && mv > topv[lrow][j]) p = j;
            for (int j = 5; j > p; --j) {
              topv[lrow][j] = topv[lrow][j - 1];
              topi[lrow][j] = topi[lrow][j - 1];
            }
            topv[lrow][p] = mv;
            topi[lrow][p] = mc;
          }
          if (bcol == mc) {  // owner lane: disable and recompute local best
#pragma unroll
            for (int f = 0; f < 4; ++f)
              if (col0 + f * 16 + ml == mc) acc[f][i] = -3e38f;
            bv = acc[0][i];
            bc = 0;
#pragma unroll
            for (int f = 1; f < 4; ++f)
              if (acc[f][i] > bv) { bv = acc[f][i]; bc = f; }
            bcol = col0 + bc * 16 + ml;
          }
          thr = topv[lrow][5];
        }
      }
    }
  }

  if constexpr (MODE >= 2) {
    __syncthreads();
    int part = blockIdx.y;
    for (int i = tid; i < 64 * 6; i += 256) {
      int r = i / 6, j = i % 6;
      size_t o = ((size_t)(row0 + r) * nparts + part) * 6 + j;
      part_vals[o] = topv[r][j];
      part_idx[o] = topi[r][j];
    }
    if constexpr (MODE == 3) {
      if (tid < 64) rowsum_part[(size_t)(row0 + tid) * nparts + part] = rsum[tid];
    }
  }
}

// ---------------------------------------------------------------------------
// Merge per-part top-6 lists (tie: value desc, index asc) + optional rowsum sum
// ---------------------------------------------------------------------------
__global__ void merge_top6_kernel(const float* __restrict__ part_vals,
                                  const int* __restrict__ part_idx, int* __restrict__ out_idx,
                                  const float* __restrict__ rowsum_part, float* __restrict__ rowsum,
                                  int nparts, int do_rowsum) {
  int row = blockIdx.x * blockDim.x + threadIdx.x;
  if (row >= 8192) return;
  float v[6];
  int id[6];
#pragma unroll
  for (int j = 0; j < 6; ++j) { v[j] = -3e38f; id[j] = 0; }
  for (int p = 0; p < nparts; ++p) {
#pragma unroll
    for (int c = 0; c < 6; ++c) {
      float cv = part_vals[((size_t)row * nparts + p) * 6 + c];
      int ci = part_idx[((size_t)row * nparts + p) * 6 + c];
      int pos = 6;
#pragma unroll
      for (int j = 0; j < 6; ++j)
        if (pos == 6 && (cv > v[j] || (cv == v[j] && ci < id[j]))) pos = j;
      if (pos < 6) {
#pragma unroll
        for (int j = 5; j >= 1; --j)
          if (j > pos) { v[j] = v[j - 1]; id[j] = id[j - 1]; }
#pragma unroll
        for (int j = 0; j < 6; ++j)
          if (j == pos) { v[j] = cv; id[j] = ci; }
      }
    }
  }
#pragma unroll
  for (int j = 0; j < 6; ++j) out_idx[row * 6 + j] = id[j];
  if (do_rowsum) {
    float s = 0.f;
    for (int p = 0; p < nparts; ++p) s += rowsum_part[(size_t)row * nparts + p];
    rowsum[row] = s;
  }
}

// ---------------------------------------------------------------------------
// Final loss: per row gather 6x6 neighbors, recompute 36 dots, -log(pos/rowsum)
// One wave per row.
// ---------------------------------------------------------------------------
__global__ void loss_kernel(const bf16* __restrict__ strun, const bf16* __restrict__ mmn,
                            const int* __restrict__ top6, const int* __restrict__ nbr,
                            const float* __restrict__ rowsum, float* __restrict__ out0) {
  int w = (int)((blockIdx.x * blockDim.x + threadIdx.x) >> 6);
  int lane = threadIdx.x & 63;
  if (w >= 8192) return;
  bf16x8 sv = *(const bf16x8*)(strun + (size_t)w * 512 + lane * 8);
  float sf[8];
#pragma unroll
  for (int e = 0; e < 8; ++e) sf[e] = (float)sv[e];
  float pos = 0.f;
  for (int k = 0; k < 6; ++k) {
    int j = top6[w * 6 + k];
#pragma unroll
    for (int l = 0; l < 6; ++l) {
      int m = nbr[j * 6 + l];
      bf16x8 mv = *(const bf16x8*)(mmn + (size_t)m * 512 + lane * 8);
      float d = 0.f;
#pragma unroll
      for (int e = 0; e < 8; ++e) d += sf[e] * (float)mv[e];
      d += __shfl_xor(d, 1);
      d += __shfl_xor(d, 2);
      d += __shfl_xor(d, 4);
      d += __shfl_xor(d, 8);
      d += __shfl_xor(d, 16);
      d += __shfl_xor(d, 32);
      pos += __expf(2.0f * d);
    }
  }
  if (lane == 0) {
    float loss_r = logf(rowsum[w]) - logf(pos);
    atomicAdd(out0, loss_r * (1.0f / 8192.0f));
  }
}

// ---------------------------------------------------------------------------
extern "C" void kernel_launch(void* const* d_in, const int* in_sizes, int n_in, void* d_out,
                              int out_size, void* d_ws, size_t ws_size, hipStream_t stream) {
  const float* stru = (const float*)d_in[0];
  const float* visu = (const float*)d_in[1];
  const float* ling = (const float*)d_in[2];
  const float* Wl1 = (const float*)d_in[3];
  const float* bl1 = (const float*)d_in[4];
  const float* Wl2 = (const float*)d_in[5];
  const float* bl2 = (const float*)d_in[6];
  const float* gl = (const float*)d_in[7];
  const float* betal = (const float*)d_in[8];
  const float* Wv1 = (const float*)d_in[9];
  const float* bv1 = (const float*)d_in[10];
  const float* Wv2 = (const float*)d_in[11];
  const float* bv2 = (const float*)d_in[12];
  const float* gv = (const float*)d_in[13];
  const float* betav = (const float*)d_in[14];
  float* out = (float*)d_out;

  char* p = (char*)d_ws;
  auto alloc = [&](size_t bytes) {
    char* r = p;
    p += (bytes + 255) & ~(size_t)255;
    return r;
  };
  bf16* strun = (bf16*)alloc((size_t)8192 * 512 * 2);
  bf16* W1t = (bf16*)alloc((size_t)512 * 4096 * 2);
  bf16* W2t = (bf16*)alloc((size_t)512 * 512 * 2);
  bf16* H1 = (bf16*)alloc((size_t)8192 * 512 * 2);
  float* H2 = (float*)alloc((size_t)8192 * 512 * 4);
  bf16* mmn = (bf16*)alloc((size_t)8192 * 512 * 2);
  float* colsum = (float*)alloc(512 * 4);
  float* colsumsq = (float*)alloc(512 * 4);
  float* rowsum_part = (float*)alloc((size_t)8192 * 8 * 4);
  float* rowsum = (float*)alloc((size_t)8192 * 4);
  float* part_vals = (float*)alloc((size_t)8192 * 8 * 6 * 4);
  int* part_idx = (int*)alloc((size_t)8192 * 8 * 6 * 4);
  int* nbr = (int*)alloc((size_t)8192 * 6 * 4);
  int* top6 = (int*)alloc((size_t)8192 * 6 * 4);

  hipMemsetAsync(d_out, 0, 4, stream);
  row_normalize_kernel<<<8192, 256, 0, stream>>>(stru, strun);

  for (int br = 0; br < 2; ++br) {
    const float* X = (br == 0) ? ling : visu;
    int Kin = (br == 0) ? 768 : 4096;
    const float* W1 = (br == 0) ? Wl1 : Wv1;
    const float* b1 = (br == 0) ? bl1 : bv1;
    const float* W2 = (br == 0) ? Wl2 : Wv2;
    const float* b2 = (br == 0) ? bl2 : bv2;
    const float* g = (br == 0) ? gl : gv;
    const float* bet = (br == 0) ? betal : betav;
    float* mm_out = out + 1 + (size_t)br * 8192 * 512;

    transpose_cast_kernel<<<dim3(Kin / 64, 8), 256, 0, stream>>>(W1, W1t, Kin);
    transpose_cast_kernel<<<dim3(8, 8), 256, 0, stream>>>(W2, W2t, 512);

    gemm_nt_kernel<0, true><<<dim3(128, 8), 256, 0, stream>>>(
        X, W1t, b1, H1, nullptr, nullptr, nullptr, nullptr, Kin, 1, 8);
    gemm_nt_kernel<1, false><<<dim3(128, 8), 256, 0, stream>>>(
        H1, W2t, b2, nullptr, H2, nullptr, nullptr, nullptr, 512, 1, 8);

    hipMemsetAsync(colsum, 0, 512 * 4, stream);
    hipMemsetAsync(colsumsq, 0, 512 * 4, stream);
    bn_stats_kernel<<<256, 512, 0, stream>>>(H2, colsum, colsumsq);
    bn_apply_kernel<<<8192, 512, 0, stream>>>(H2, colsum, colsumsq, g, bet, mm_out, mmn);

    // neighbor table: top-6 of each row of mmn @ mmn^T
    gemm_nt_kernel<2, false><<<dim3(128, 8), 256, 0, stream>>>(
        mmn, mmn, nullptr, nullptr, nullptr, part_vals, part_idx, nullptr, 512, 16, 8);
    merge_top6_kernel<<<32, 256, 0, stream>>>(part_vals, part_idx, nbr, nullptr, nullptr, 8, 0);

    // sm pass: rowsum + top-6 of strun @ mmn^T
    gemm_nt_kernel<3, false><<<dim3(128, 8), 256, 0, stream>>>(
        strun, mmn, nullptr, nullptr, nullptr, part_vals, part_idx, rowsum_part, 512, 16, 8);
    merge_top6_kernel<<<32, 256, 0, stream>>>(part_vals, part_idx, top6, rowsum_part, rowsum, 8, 1);

    loss_kernel<<<2048, 256, 0, stream>>>(strun, mmn, top6, nbr, rowsum, out);
  }
}